// Round 1
// baseline (234.259 us; speedup 1.0000x reference)
//
#include <hip/hip_runtime.h>

#define BB 8
#define PP 4096
#define DD 256
#define CC 1024

#define TM 128  // p rows per block
#define TN 128  // c cols per block
#define TK 16   // k chunk

// ---------------------------------------------------------------------------
// init argmax cells: key = (float_bits(0.0f)<<32) | ~0u  -> value 0.0 at p=0
// ---------------------------------------------------------------------------
__global__ __launch_bounds__(256) void init_ws_kernel(unsigned long long* keys, int n) {
    int i = blockIdx.x * 256 + threadIdx.x;
    if (i < n) keys[i] = 0x00000000FFFFFFFFull;
}

// ---------------------------------------------------------------------------
// fused fp32 GEMM (scores = relu(x @ W^T)) + per-column argmax over the
// block's 128 p-rows, merged into global keys[b*C + c] via u64 atomicMax.
// key = (bits(relu_score) << 32) | (0xFFFFFFFF - p)   (ties -> lowest p wins)
// ---------------------------------------------------------------------------
__global__ __launch_bounds__(256) void gemm_argmax_kernel(
    const float* __restrict__ x,   // [B, P, D]
    const float* __restrict__ W,   // [C, D]
    unsigned long long* __restrict__ keys)  // [B*C]
{
    __shared__ float xs[TK][TM];     // transposed x tile
    __shared__ float wsm[TK][TN];    // transposed W tile
    __shared__ unsigned long long smax[TN];

    const int tid = threadIdx.x;
    const int tx = tid & 15;         // col group
    const int ty = tid >> 4;         // row group
    const int c0 = blockIdx.x * TN;
    const int p0 = blockIdx.y * TM;
    const int b  = blockIdx.z;

    const float* xb = x + (size_t)b * PP * DD;

    float acc[8][8];
    #pragma unroll
    for (int i = 0; i < 8; i++)
        #pragma unroll
        for (int j = 0; j < 8; j++) acc[i][j] = 0.f;

    for (int k0 = 0; k0 < DD; k0 += TK) {
        // stage x tile: 128 rows x 16 k, transposed into xs[k][row]
        #pragma unroll
        for (int l = 0; l < 2; l++) {
            int lid = tid + l * 256;
            int r = lid >> 2, q = lid & 3;
            float4 v = *reinterpret_cast<const float4*>(xb + (size_t)(p0 + r) * DD + k0 + q * 4);
            xs[q * 4 + 0][r] = v.x;
            xs[q * 4 + 1][r] = v.y;
            xs[q * 4 + 2][r] = v.z;
            xs[q * 4 + 3][r] = v.w;
        }
        // stage W tile: 128 cols x 16 k, transposed into wsm[k][col]
        #pragma unroll
        for (int l = 0; l < 2; l++) {
            int lid = tid + l * 256;
            int r = lid >> 2, q = lid & 3;
            float4 v = *reinterpret_cast<const float4*>(W + (size_t)(c0 + r) * DD + k0 + q * 4);
            wsm[q * 4 + 0][r] = v.x;
            wsm[q * 4 + 1][r] = v.y;
            wsm[q * 4 + 2][r] = v.z;
            wsm[q * 4 + 3][r] = v.w;
        }
        __syncthreads();

        #pragma unroll
        for (int k = 0; k < TK; k++) {
            float a[8], bf[8];
            #pragma unroll
            for (int i = 0; i < 8; i++) a[i] = xs[k][ty * 8 + i];
            #pragma unroll
            for (int j = 0; j < 8; j++) bf[j] = wsm[k][tx * 8 + j];
            #pragma unroll
            for (int i = 0; i < 8; i++)
                #pragma unroll
                for (int j = 0; j < 8; j++)
                    acc[i][j] = fmaf(a[i], bf[j], acc[i][j]);
        }
        __syncthreads();
    }

    // block-local argmax per column
    if (tid < TN) smax[tid] = 0ull;
    __syncthreads();

    #pragma unroll
    for (int j = 0; j < 8; j++) {
        // reduce this thread's 8 rows for column tx*8+j; lowest p wins ties
        float best = fmaxf(acc[0][j], 0.f);
        int bi = 0;
        #pragma unroll
        for (int i = 1; i < 8; i++) {
            float v = fmaxf(acc[i][j], 0.f);
            if (v > best) { best = v; bi = i; }
        }
        unsigned int p = (unsigned int)(p0 + ty * 8 + bi);
        unsigned long long key =
            ((unsigned long long)__float_as_uint(best) << 32) | (0xFFFFFFFFu - p);
        atomicMax(&smax[tx * 8 + j], key);
    }
    __syncthreads();

    if (tid < TN) {
        atomicMax(&keys[(size_t)b * CC + c0 + tid], smax[tid]);
    }
}

// ---------------------------------------------------------------------------
// scatter: out[b, argmax_p(b,c), :] += W[c, :]
// ---------------------------------------------------------------------------
__global__ __launch_bounds__(64) void scatter_kernel(
    const unsigned long long* __restrict__ keys,
    const float* __restrict__ W,
    float* __restrict__ out)
{
    const int cell = blockIdx.x;           // b*C + c
    const int c = cell & (CC - 1);
    const int b = cell >> 10;
    unsigned long long key = keys[cell];
    unsigned int p = (0xFFFFFFFFu - (unsigned int)(key & 0xFFFFFFFFull)) & (PP - 1);

    const float* wrow = W + (size_t)c * DD;
    float* orow = out + ((size_t)b * PP + p) * DD;
    const int t = threadIdx.x;
    #pragma unroll
    for (int u = 0; u < 4; u++) {
        int idx = u * 64 + t;              // fully coalesced per u
        atomicAdd(&orow[idx], wrow[idx]);
    }
}

extern "C" void kernel_launch(void* const* d_in, const int* in_sizes, int n_in,
                              void* d_out, int out_size, void* d_ws, size_t ws_size,
                              hipStream_t stream) {
    const float* x = (const float*)d_in[0];   // [B, P, D] fp32
    const float* W = (const float*)d_in[1];   // [C, D]    fp32
    float* out = (float*)d_out;               // [B, P, D] fp32
    unsigned long long* keys = (unsigned long long*)d_ws;  // B*C cells

    // zero output (harness does not re-zero between replays)
    hipMemsetAsync(d_out, 0, (size_t)out_size * sizeof(float), stream);

    // init argmax cells
    {
        int n = BB * CC;
        init_ws_kernel<<<(n + 255) / 256, 256, 0, stream>>>(keys, n);
    }

    // fused GEMM + argmax
    {
        dim3 grid(CC / TN, PP / TM, BB);
        gemm_argmax_kernel<<<grid, 256, 0, stream>>>(x, W, keys);
    }

    // scatter W rows
    {
        dim3 grid(BB * CC);
        scatter_kernel<<<grid, 64, 0, stream>>>(keys, W, out);
    }
}

// Round 2
// 115.095 us; speedup vs baseline: 2.0354x; 2.0354x over previous
//
#include <hip/hip_runtime.h>

#define BB 8
#define PP 4096
#define DD 256
#define CC 1024

#define TM 128
#define TN 128
#define BK 64
#define NSTAGE (DD / BK)   // 4

typedef _Float16 f16x8 __attribute__((ext_vector_type(8)));
typedef float f32x16 __attribute__((ext_vector_type(16)));

// ---------------------------------------------------------------------------
// init argmax cells: key = (bits(0.0f)<<32) | (0xFFFFFFFF - 0) -> score 0 @ p=0
// ---------------------------------------------------------------------------
__global__ __launch_bounds__(256) void init_ws_kernel(unsigned long long* keys, int n) {
    int i = blockIdx.x * 256 + threadIdx.x;
    if (i < n) keys[i] = 0x00000000FFFFFFFFull;
}

// ---------------------------------------------------------------------------
// fused GEMM (fp16 split-MFMA, scores = relu(x @ W^T)) + per-column argmax.
// x = h + 2^-12 * l (both fp16, l pre-scaled by 2^12). 3 MFMA passes:
//   acc_hi += hx*hw ; acc_lo += hx*lw + lx*hw ; score = acc_hi + acc_lo/4096
// LDS layout is fragment-contiguous: lA[kk][rowtile][split][slot] of f16x8,
// where slot = (row&31) + 32*(k8half) -> fragment read is a linear
// ds_read_b128 at lane*16 (conflict-free), matching mfma_32x32x16 A/B layout
// (lane l: row/col = l&31, k = 8*(l>>5)+j).
// ---------------------------------------------------------------------------
__global__ __launch_bounds__(256, 2) void gemm_argmax_kernel(
    const float* __restrict__ x,   // [B, P, D]
    const float* __restrict__ W,   // [C, D]
    unsigned long long* __restrict__ keys)  // [B*C]
{
    __shared__ f16x8 lA[4][4][2][64];   // [kk][rowtile][split][slot]  32 KB
    __shared__ f16x8 lB[4][4][2][64];   // [kk][coltile][split][slot]  32 KB

    const int tid = threadIdx.x;
    const int lane = tid & 63;
    const int w = tid >> 6;            // wave id 0..3
    const int wy = w >> 1, wx = w & 1; // 2x2 wave grid, each wave 64x64 out
    const int c0 = blockIdx.x * TN;
    const int p0 = blockIdx.y * TM;
    const int b  = blockIdx.z;

    const float* xb = x + (size_t)b * PP * DD;

    f32x16 zero;
    #pragma unroll
    for (int i = 0; i < 16; ++i) zero[i] = 0.f;
    f32x16 acc_hi[2][2], acc_lo[2][2];
    #pragma unroll
    for (int i = 0; i < 2; ++i)
        #pragma unroll
        for (int j = 0; j < 2; ++j) { acc_hi[i][j] = zero; acc_lo[i][j] = zero; }

    for (int st = 0; st < NSTAGE; ++st) {
        const int k0 = st * BK;
        float4 gA[8], gB[8];
        #pragma unroll
        for (int v = 0; v < 4; ++v) {
            int pi = tid + 256 * v;          // 0..1023
            int r  = pi >> 3;                // 0..127
            int ck = (pi & 7) * 8;           // k chunk of 8 within BK
            const float* pa = xb + (size_t)(p0 + r) * DD + k0 + ck;
            gA[2 * v]     = *reinterpret_cast<const float4*>(pa);
            gA[2 * v + 1] = *reinterpret_cast<const float4*>(pa + 4);
            const float* pb = W + (size_t)(c0 + r) * DD + k0 + ck;
            gB[2 * v]     = *reinterpret_cast<const float4*>(pb);
            gB[2 * v + 1] = *reinterpret_cast<const float4*>(pb + 4);
        }
        __syncthreads();   // previous stage's compute done reading LDS
        #pragma unroll
        for (int v = 0; v < 4; ++v) {
            int pi = tid + 256 * v;
            int r  = pi >> 3;
            int ph = pi & 7;                 // which 8-k chunk
            int kk = ph >> 1;                // 16-k step index 0..3
            int half = ph & 1;               // which 8 of the 16 k
            int slot = (r & 31) + 32 * half;
            int rtp = r >> 5;                // row-tile 0..3

            float va[8] = {gA[2*v].x, gA[2*v].y, gA[2*v].z, gA[2*v].w,
                           gA[2*v+1].x, gA[2*v+1].y, gA[2*v+1].z, gA[2*v+1].w};
            f16x8 h1, h2;
            #pragma unroll
            for (int i = 0; i < 8; ++i) {
                _Float16 h = (_Float16)va[i];
                h1[i] = h;
                h2[i] = (_Float16)((va[i] - (float)h) * 4096.0f);
            }
            lA[kk][rtp][0][slot] = h1;
            lA[kk][rtp][1][slot] = h2;

            float vb[8] = {gB[2*v].x, gB[2*v].y, gB[2*v].z, gB[2*v].w,
                           gB[2*v+1].x, gB[2*v+1].y, gB[2*v+1].z, gB[2*v+1].w};
            f16x8 g1, g2;
            #pragma unroll
            for (int i = 0; i < 8; ++i) {
                _Float16 h = (_Float16)vb[i];
                g1[i] = h;
                g2[i] = (_Float16)((vb[i] - (float)h) * 4096.0f);
            }
            lB[kk][rtp][0][slot] = g1;
            lB[kk][rtp][1][slot] = g2;
        }
        __syncthreads();

        #pragma unroll
        for (int kk = 0; kk < 4; ++kk) {
            f16x8 xa[2][2], wb[2][2];
            #pragma unroll
            for (int rt = 0; rt < 2; ++rt) {
                xa[rt][0] = lA[kk][wy * 2 + rt][0][lane];
                xa[rt][1] = lA[kk][wy * 2 + rt][1][lane];
            }
            #pragma unroll
            for (int ct = 0; ct < 2; ++ct) {
                wb[ct][0] = lB[kk][wx * 2 + ct][0][lane];
                wb[ct][1] = lB[kk][wx * 2 + ct][1][lane];
            }
            #pragma unroll
            for (int rt = 0; rt < 2; ++rt)
                #pragma unroll
                for (int ct = 0; ct < 2; ++ct) {
                    acc_hi[rt][ct] = __builtin_amdgcn_mfma_f32_32x32x16_f16(
                        xa[rt][0], wb[ct][0], acc_hi[rt][ct], 0, 0, 0);
                    acc_lo[rt][ct] = __builtin_amdgcn_mfma_f32_32x32x16_f16(
                        xa[rt][0], wb[ct][1], acc_lo[rt][ct], 0, 0, 0);
                    acc_lo[rt][ct] = __builtin_amdgcn_mfma_f32_32x32x16_f16(
                        xa[rt][1], wb[ct][0], acc_lo[rt][ct], 0, 0, 0);
                }
        }
    }

    // ---- epilogue: per-column argmax over this block's 128 rows ----
    // reuse lA storage for the 128 u64 column cells (compute is done with LDS
    // after the final barrier below)
    unsigned long long* smax = reinterpret_cast<unsigned long long*>(&lA[0][0][0][0]);
    __syncthreads();                 // all waves done reading lA/lB
    if (tid < TN) smax[tid] = 0ull;
    __syncthreads();

    #pragma unroll
    for (int ct = 0; ct < 2; ++ct) {
        unsigned long long bk = 0ull;
        #pragma unroll
        for (int rt = 0; rt < 2; ++rt) {
            f32x16 h = acc_hi[rt][ct];
            f32x16 l = acc_lo[rt][ct];
            #pragma unroll
            for (int reg = 0; reg < 16; ++reg) {
                float v = fmaxf(h[reg] + l[reg] * (1.0f / 4096.0f), 0.f);
                int prow = p0 + (wy * 2 + rt) * 32 +
                           (reg & 3) + 8 * (reg >> 2) + 4 * (lane >> 5);
                unsigned long long key =
                    ((unsigned long long)__float_as_uint(v) << 32) |
                    (unsigned int)(0xFFFFFFFFu - (unsigned int)prow);
                bk = bk > key ? bk : key;
            }
        }
        unsigned long long other = __shfl_xor(bk, 32, 64);
        bk = bk > other ? bk : other;
        if (lane < 32) {
            int col = (wx * 2 + ct) * 32 + (lane & 31);
            atomicMax(&smax[col], bk);
        }
    }
    __syncthreads();
    if (tid < TN) {
        atomicMax(&keys[(size_t)b * CC + c0 + tid], smax[tid]);
    }
}

// ---------------------------------------------------------------------------
// scatter: out[b, argmax_p(b,c), :] += W[c, :]
// ---------------------------------------------------------------------------
__global__ __launch_bounds__(64) void scatter_kernel(
    const unsigned long long* __restrict__ keys,
    const float* __restrict__ W,
    float* __restrict__ out)
{
    const int cell = blockIdx.x;           // b*C + c
    const int c = cell & (CC - 1);
    const int b = cell >> 10;
    unsigned long long key = keys[cell];
    unsigned int p = (0xFFFFFFFFu - (unsigned int)(key & 0xFFFFFFFFull)) & (PP - 1);

    const float* wrow = W + (size_t)c * DD;
    float* orow = out + ((size_t)b * PP + p) * DD;
    const int t = threadIdx.x;
    #pragma unroll
    for (int u = 0; u < 4; u++) {
        int idx = u * 64 + t;              // coalesced per u
        atomicAdd(&orow[idx], wrow[idx]);
    }
}

extern "C" void kernel_launch(void* const* d_in, const int* in_sizes, int n_in,
                              void* d_out, int out_size, void* d_ws, size_t ws_size,
                              hipStream_t stream) {
    const float* x = (const float*)d_in[0];   // [B, P, D] fp32
    const float* W = (const float*)d_in[1];   // [C, D]    fp32
    float* out = (float*)d_out;               // [B, P, D] fp32
    unsigned long long* keys = (unsigned long long*)d_ws;  // B*C cells

    hipMemsetAsync(d_out, 0, (size_t)out_size * sizeof(float), stream);

    {
        int n = BB * CC;
        init_ws_kernel<<<(n + 255) / 256, 256, 0, stream>>>(keys, n);
    }
    {
        dim3 grid(CC / TN, PP / TM, BB);
        gemm_argmax_kernel<<<grid, 256, 0, stream>>>(x, W, keys);
    }
    {
        dim3 grid(BB * CC);
        scatter_kernel<<<grid, 64, 0, stream>>>(keys, W, out);
    }
}

// Round 3
// 108.832 us; speedup vs baseline: 2.1525x; 1.0575x over previous
//
#include <hip/hip_runtime.h>
#include <cstdint>

#define BB 8
#define PP 4096
#define DD 256
#define CC 1024

#define TM 128
#define TN 128
#define BK 64
#define NSTAGE (DD / BK)   // 4

#define XN (BB * PP * DD)  // 8388608
#define WN (CC * DD)       // 262144

typedef _Float16 f16x8 __attribute__((ext_vector_type(8)));
typedef float f32x16 __attribute__((ext_vector_type(16)));
typedef unsigned long long u64;

__device__ __forceinline__ void async_load16(const void* src, void* lds_dst) {
    __builtin_amdgcn_global_load_lds(
        (const __attribute__((address_space(1))) uint32_t*)src,
        (__attribute__((address_space(3))) uint32_t*)lds_dst,
        16, 0, 0);
}

// ---------------------------------------------------------------------------
// init argmax cells: key = (bits(0.0f)<<32) | (0xFFFFFFFF - 0) -> score 0 @ p=0
// ---------------------------------------------------------------------------
__global__ __launch_bounds__(256) void init_ws_kernel(u64* keys, int n) {
    int i = blockIdx.x * 256 + threadIdx.x;
    if (i < n) keys[i] = 0x00000000FFFFFFFFull;
}

// ---------------------------------------------------------------------------
// pre-split: v = h + 2^-12 * l, h/l fp16, l pre-scaled by 4096.
// covers x (XN elems) then W (WN elems), 8 elems/thread, fully vectorized.
// ---------------------------------------------------------------------------
__global__ __launch_bounds__(256) void split_kernel(
    const float* __restrict__ x, const float* __restrict__ W,
    _Float16* __restrict__ xh, _Float16* __restrict__ xl,
    _Float16* __restrict__ wh, _Float16* __restrict__ wl)
{
    size_t g = ((size_t)blockIdx.x * 256 + threadIdx.x) * 8;
    const float* src;
    _Float16 *dh, *dl;
    if (g < (size_t)XN) {
        src = x + g; dh = xh + g; dl = xl + g;
    } else {
        size_t o = g - XN;
        if (o >= (size_t)WN) return;
        src = W + o; dh = wh + o; dl = wl + o;
    }
    float4 a = *reinterpret_cast<const float4*>(src);
    float4 b = *reinterpret_cast<const float4*>(src + 4);
    float va[8] = {a.x, a.y, a.z, a.w, b.x, b.y, b.z, b.w};
    f16x8 h, l;
    #pragma unroll
    for (int i = 0; i < 8; ++i) {
        _Float16 hv = (_Float16)va[i];
        h[i] = hv;
        l[i] = (_Float16)((va[i] - (float)hv) * 4096.0f);
    }
    *reinterpret_cast<f16x8*>(dh) = h;
    *reinterpret_cast<f16x8*>(dl) = l;
}

// ---------------------------------------------------------------------------
// main: fp16-split MFMA GEMM (scores = relu(x @ W^T)) + per-column argmax,
// staging via global_load_lds into fragment-contiguous LDS (no ds_writes).
// LDS block (kk, rowtile, split) = 64 slots x 16B; lane l -> slot l, matching
// mfma_32x32x16 A/B fragment layout (row = l&31, k = kk*16 + (l>>5)*8 + j).
// ---------------------------------------------------------------------------
__global__ __launch_bounds__(256, 2) void gemm_argmax_lds_kernel(
    const _Float16* __restrict__ xh, const _Float16* __restrict__ xl,
    const _Float16* __restrict__ wh, const _Float16* __restrict__ wl,
    u64* __restrict__ keys)
{
    __shared__ f16x8 lA[4][4][2][64];   // [kk][rowtile][split][slot]  32 KB
    __shared__ f16x8 lB[4][4][2][64];   // 32 KB

    const int tid = threadIdx.x;
    const int lane = tid & 63;
    const int w = tid >> 6;
    const int wy = w >> 1, wx = w & 1;
    const int p0 = blockIdx.x * TM;     // x fastest -> c-blocks of same A tile
    const int c0 = blockIdx.y * TN;     //   land on same XCD (bid stride 32)
    const int b  = blockIdx.z;

    // per-lane source offset within a (rt,kk) block: row (l&31), k-half (l>>5)
    const int lane_off = (lane & 31) * DD + (lane >> 5) * 8;

    const _Float16* sA0 = xh + (size_t)b * PP * DD + (size_t)p0 * DD;
    const _Float16* sA1 = xl + (size_t)b * PP * DD + (size_t)p0 * DD;
    const _Float16* sB0 = wh + (size_t)c0 * DD;
    const _Float16* sB1 = wl + (size_t)c0 * DD;

    const int m_sel = w >> 1;          // waves 0,1 stage A; waves 2,3 stage B
    const int kkb = (w & 1) * 2;       // each wave covers 2 of the 4 kk

    f32x16 zero;
    #pragma unroll
    for (int i = 0; i < 16; ++i) zero[i] = 0.f;
    f32x16 acc_hi[2][2], acc_lo[2][2];
    #pragma unroll
    for (int i = 0; i < 2; ++i)
        #pragma unroll
        for (int j = 0; j < 2; ++j) { acc_hi[i][j] = zero; acc_lo[i][j] = zero; }

    for (int st = 0; st < NSTAGE; ++st) {
        const int k0 = st * BK;
        __syncthreads();   // previous stage's LDS reads complete
        #pragma unroll
        for (int i = 0; i < 16; ++i) {
            const int kk = kkb + (i >> 3);
            const int rt = (i >> 1) & 3;
            const int sp = i & 1;
            const _Float16* src =
                (m_sel ? (sp ? sB1 : sB0) : (sp ? sA1 : sA0))
                + rt * 32 * DD + k0 + kk * 16 + lane_off;
            void* dst = m_sel ? (void*)&lB[kk][rt][sp][0]
                              : (void*)&lA[kk][rt][sp][0];
            async_load16(src, dst);
        }
        __syncthreads();   // vmcnt(0) drain: tiles landed

        #pragma unroll
        for (int kk = 0; kk < 4; ++kk) {
            f16x8 xa[2][2], wb2[2][2];
            #pragma unroll
            for (int rt = 0; rt < 2; ++rt) {
                xa[rt][0] = lA[kk][wy * 2 + rt][0][lane];
                xa[rt][1] = lA[kk][wy * 2 + rt][1][lane];
            }
            #pragma unroll
            for (int ct = 0; ct < 2; ++ct) {
                wb2[ct][0] = lB[kk][wx * 2 + ct][0][lane];
                wb2[ct][1] = lB[kk][wx * 2 + ct][1][lane];
            }
            #pragma unroll
            for (int rt = 0; rt < 2; ++rt)
                #pragma unroll
                for (int ct = 0; ct < 2; ++ct) {
                    acc_hi[rt][ct] = __builtin_amdgcn_mfma_f32_32x32x16_f16(
                        xa[rt][0], wb2[ct][0], acc_hi[rt][ct], 0, 0, 0);
                    acc_lo[rt][ct] = __builtin_amdgcn_mfma_f32_32x32x16_f16(
                        xa[rt][0], wb2[ct][1], acc_lo[rt][ct], 0, 0, 0);
                    acc_lo[rt][ct] = __builtin_amdgcn_mfma_f32_32x32x16_f16(
                        xa[rt][1], wb2[ct][0], acc_lo[rt][ct], 0, 0, 0);
                }
        }
    }

    // ---- epilogue: per-column argmax over this block's 128 rows ----
    u64* smax = reinterpret_cast<u64*>(&lA[0][0][0][0]);
    __syncthreads();
    if (tid < TN) smax[tid] = 0ull;
    __syncthreads();

    #pragma unroll
    for (int ct = 0; ct < 2; ++ct) {
        u64 bk = 0ull;
        #pragma unroll
        for (int rt = 0; rt < 2; ++rt) {
            f32x16 h = acc_hi[rt][ct];
            f32x16 l = acc_lo[rt][ct];
            #pragma unroll
            for (int reg = 0; reg < 16; ++reg) {
                float v = fmaxf(h[reg] + l[reg] * (1.0f / 4096.0f), 0.f);
                int prow = p0 + (wy * 2 + rt) * 32 +
                           (reg & 3) + 8 * (reg >> 2) + 4 * (lane >> 5);
                u64 key = ((u64)__float_as_uint(v) << 32) |
                          (unsigned int)(0xFFFFFFFFu - (unsigned int)prow);
                bk = bk > key ? bk : key;
            }
        }
        u64 other = __shfl_xor(bk, 32, 64);
        bk = bk > other ? bk : other;
        if (lane < 32) {
            int col = (wx * 2 + ct) * 32 + (lane & 31);
            atomicMax(&smax[col], bk);
        }
    }
    __syncthreads();
    if (tid < TN) {
        atomicMax(&keys[(size_t)b * CC + c0 + tid], smax[tid]);
    }
}

// ---------------------------------------------------------------------------
// fallback (ws too small): round-2 kernel, in-kernel conversion
// ---------------------------------------------------------------------------
__global__ __launch_bounds__(256, 2) void gemm_argmax_conv_kernel(
    const float* __restrict__ x, const float* __restrict__ W,
    u64* __restrict__ keys)
{
    __shared__ f16x8 lA[4][4][2][64];
    __shared__ f16x8 lB[4][4][2][64];

    const int tid = threadIdx.x;
    const int lane = tid & 63;
    const int w = tid >> 6;
    const int wy = w >> 1, wx = w & 1;
    const int p0 = blockIdx.x * TM;
    const int c0 = blockIdx.y * TN;
    const int b  = blockIdx.z;

    const float* xb = x + (size_t)b * PP * DD;

    f32x16 zero;
    #pragma unroll
    for (int i = 0; i < 16; ++i) zero[i] = 0.f;
    f32x16 acc_hi[2][2], acc_lo[2][2];
    #pragma unroll
    for (int i = 0; i < 2; ++i)
        #pragma unroll
        for (int j = 0; j < 2; ++j) { acc_hi[i][j] = zero; acc_lo[i][j] = zero; }

    for (int st = 0; st < NSTAGE; ++st) {
        const int k0 = st * BK;
        float4 gA[8], gB[8];
        #pragma unroll
        for (int v = 0; v < 4; ++v) {
            int pi = tid + 256 * v;
            int r  = pi >> 3;
            int ck = (pi & 7) * 8;
            const float* pa = xb + (size_t)(p0 + r) * DD + k0 + ck;
            gA[2 * v]     = *reinterpret_cast<const float4*>(pa);
            gA[2 * v + 1] = *reinterpret_cast<const float4*>(pa + 4);
            const float* pb = W + (size_t)(c0 + r) * DD + k0 + ck;
            gB[2 * v]     = *reinterpret_cast<const float4*>(pb);
            gB[2 * v + 1] = *reinterpret_cast<const float4*>(pb + 4);
        }
        __syncthreads();
        #pragma unroll
        for (int v = 0; v < 4; ++v) {
            int pi = tid + 256 * v;
            int r  = pi >> 3;
            int ph = pi & 7;
            int kk = ph >> 1;
            int half = ph & 1;
            int slot = (r & 31) + 32 * half;
            int rtp = r >> 5;
            float va[8] = {gA[2*v].x, gA[2*v].y, gA[2*v].z, gA[2*v].w,
                           gA[2*v+1].x, gA[2*v+1].y, gA[2*v+1].z, gA[2*v+1].w};
            f16x8 h1, h2;
            #pragma unroll
            for (int i = 0; i < 8; ++i) {
                _Float16 h = (_Float16)va[i];
                h1[i] = h;
                h2[i] = (_Float16)((va[i] - (float)h) * 4096.0f);
            }
            lA[kk][rtp][0][slot] = h1;
            lA[kk][rtp][1][slot] = h2;
            float vb[8] = {gB[2*v].x, gB[2*v].y, gB[2*v].z, gB[2*v].w,
                           gB[2*v+1].x, gB[2*v+1].y, gB[2*v+1].z, gB[2*v+1].w};
            f16x8 g1, g2;
            #pragma unroll
            for (int i = 0; i < 8; ++i) {
                _Float16 h = (_Float16)vb[i];
                g1[i] = h;
                g2[i] = (_Float16)((vb[i] - (float)h) * 4096.0f);
            }
            lB[kk][rtp][0][slot] = g1;
            lB[kk][rtp][1][slot] = g2;
        }
        __syncthreads();
        #pragma unroll
        for (int kk = 0; kk < 4; ++kk) {
            f16x8 xa[2][2], wb2[2][2];
            #pragma unroll
            for (int rt = 0; rt < 2; ++rt) {
                xa[rt][0] = lA[kk][wy * 2 + rt][0][lane];
                xa[rt][1] = lA[kk][wy * 2 + rt][1][lane];
            }
            #pragma unroll
            for (int ct = 0; ct < 2; ++ct) {
                wb2[ct][0] = lB[kk][wx * 2 + ct][0][lane];
                wb2[ct][1] = lB[kk][wx * 2 + ct][1][lane];
            }
            #pragma unroll
            for (int rt = 0; rt < 2; ++rt)
                #pragma unroll
                for (int ct = 0; ct < 2; ++ct) {
                    acc_hi[rt][ct] = __builtin_amdgcn_mfma_f32_32x32x16_f16(
                        xa[rt][0], wb2[ct][0], acc_hi[rt][ct], 0, 0, 0);
                    acc_lo[rt][ct] = __builtin_amdgcn_mfma_f32_32x32x16_f16(
                        xa[rt][0], wb2[ct][1], acc_lo[rt][ct], 0, 0, 0);
                    acc_lo[rt][ct] = __builtin_amdgcn_mfma_f32_32x32x16_f16(
                        xa[rt][1], wb2[ct][0], acc_lo[rt][ct], 0, 0, 0);
                }
        }
    }

    u64* smax = reinterpret_cast<u64*>(&lA[0][0][0][0]);
    __syncthreads();
    if (tid < TN) smax[tid] = 0ull;
    __syncthreads();

    #pragma unroll
    for (int ct = 0; ct < 2; ++ct) {
        u64 bk = 0ull;
        #pragma unroll
        for (int rt = 0; rt < 2; ++rt) {
            f32x16 h = acc_hi[rt][ct];
            f32x16 l = acc_lo[rt][ct];
            #pragma unroll
            for (int reg = 0; reg < 16; ++reg) {
                float v = fmaxf(h[reg] + l[reg] * (1.0f / 4096.0f), 0.f);
                int prow = p0 + (wy * 2 + rt) * 32 +
                           (reg & 3) + 8 * (reg >> 2) + 4 * (lane >> 5);
                u64 key = ((u64)__float_as_uint(v) << 32) |
                          (unsigned int)(0xFFFFFFFFu - (unsigned int)prow);
                bk = bk > key ? bk : key;
            }
        }
        u64 other = __shfl_xor(bk, 32, 64);
        bk = bk > other ? bk : other;
        if (lane < 32) {
            int col = (wx * 2 + ct) * 32 + (lane & 31);
            atomicMax(&smax[col], bk);
        }
    }
    __syncthreads();
    if (tid < TN) {
        atomicMax(&keys[(size_t)b * CC + c0 + tid], smax[tid]);
    }
}

// ---------------------------------------------------------------------------
// scatter: out[b, argmax_p(b,c), :] += W[c, :]
// ---------------------------------------------------------------------------
__global__ __launch_bounds__(64) void scatter_kernel(
    const u64* __restrict__ keys,
    const float* __restrict__ W,
    float* __restrict__ out)
{
    const int cell = blockIdx.x;
    const int c = cell & (CC - 1);
    const int b = cell >> 10;
    u64 key = keys[cell];
    unsigned int p = (0xFFFFFFFFu - (unsigned int)(key & 0xFFFFFFFFull)) & (PP - 1);

    const float* wrow = W + (size_t)c * DD;
    float* orow = out + ((size_t)b * PP + p) * DD;
    const int t = threadIdx.x;
    #pragma unroll
    for (int u = 0; u < 4; u++) {
        int idx = u * 64 + t;
        atomicAdd(&orow[idx], wrow[idx]);
    }
}

extern "C" void kernel_launch(void* const* d_in, const int* in_sizes, int n_in,
                              void* d_out, int out_size, void* d_ws, size_t ws_size,
                              hipStream_t stream) {
    const float* x = (const float*)d_in[0];   // [B, P, D] fp32
    const float* W = (const float*)d_in[1];   // [C, D]    fp32
    float* out = (float*)d_out;

    char* wsb = (char*)d_ws;
    u64* keys = (u64*)wsb;                          // 64 KB
    _Float16* xh = (_Float16*)(wsb + 65536);
    _Float16* xl = xh + (size_t)XN;
    _Float16* wh = xl + (size_t)XN;
    _Float16* wl = wh + (size_t)WN;
    const size_t need = 65536 + 2 * (size_t)XN * 2 + 2 * (size_t)WN * 2;

    hipMemsetAsync(d_out, 0, (size_t)out_size * sizeof(float), stream);

    {
        int n = BB * CC;
        init_ws_kernel<<<(n + 255) / 256, 256, 0, stream>>>(keys, n);
    }

    if (ws_size >= need) {
        int groups = (XN + WN) / 8;                 // 1081344
        split_kernel<<<(groups + 255) / 256, 256, 0, stream>>>(x, W, xh, xl, wh, wl);
        dim3 grid(PP / TM, CC / TN, BB);
        gemm_argmax_lds_kernel<<<grid, 256, 0, stream>>>(xh, xl, wh, wl, keys);
    } else {
        dim3 grid(PP / TM, CC / TN, BB);
        gemm_argmax_conv_kernel<<<grid, 256, 0, stream>>>(x, W, keys);
    }

    {
        dim3 grid(BB * CC);
        scatter_kernel<<<grid, 64, 0, stream>>>(keys, W, out);
    }
}

// Round 4
// 88.000 us; speedup vs baseline: 2.6620x; 1.2367x over previous
//
#include <hip/hip_runtime.h>
#include <cstdint>

#define BB 8
#define PP 4096
#define DD 256
#define CC 1024

#define TM 128
#define TN 128

#define XT_BYTES (33554432ull)   // 8*32 tiles * 128KB
#define WT_BYTES (1048576ull)    // 8 chunks * 128KB
#define TILE_BYTES 131072ull     // one (b,pt) or cy chunk: 128 rows x 256 k x 2 planes x 2B

typedef _Float16 f16x8 __attribute__((ext_vector_type(8)));
typedef float f32x16 __attribute__((ext_vector_type(16)));
typedef unsigned long long u64;

__device__ __forceinline__ void async_load16(const void* src, void* lds_dst) {
    __builtin_amdgcn_global_load_lds(
        (const __attribute__((address_space(1))) uint32_t*)src,
        (__attribute__((address_space(3))) uint32_t*)lds_dst,
        16, 0, 0);
}

// ---------------------------------------------------------------------------
// init argmax cells: key = (bits(0.0f)<<32) | (0xFFFFFFFF - 0) -> score 0 @ p=0
// ---------------------------------------------------------------------------
__global__ __launch_bounds__(256) void init_ws_kernel(u64* keys, int n) {
    int i = blockIdx.x * 256 + threadIdx.x;
    if (i < n) keys[i] = 0x00000000FFFFFFFFull;
}

// ---------------------------------------------------------------------------
// transform: fp32 [rows][256] -> fragment-ordered fp16 hi/lo planes.
// Output chunk (st,kk,rt,sp,slot) of 16B at
//   ((((st*2+kk)*4+rt)*2+sp)*64 + slot)*16, slot = (row&31) + 32*ksub,
//   source (row = rt*32 + (slot&31), k = st*32 + kk*16 + ksub*8 .. +7).
// Each block does 64 rows (one half of a 128-row tile) via LDS transpose:
// global reads and writes both fully coalesced.
// grid = 528: ids 0..511 -> x tile (id>>1), h=id&1; 512..527 -> W chunk.
// ---------------------------------------------------------------------------
__global__ __launch_bounds__(256) void transform_kernel(
    const float* __restrict__ x, const float* __restrict__ W,
    char* __restrict__ xT, char* __restrict__ wT)
{
    __shared__ float ls[64 * 260];   // 64 rows, stride 260 (pad: f4-aligned)

    const int id = blockIdx.x;
    const int tile = id >> 1;
    const int h = id & 1;
    const float* src;
    char* dstTile;
    if (tile < 256) {
        src = x + (size_t)tile * 128 * 256;          // tile = b*32+pt
        dstTile = xT + (size_t)tile * TILE_BYTES;
    } else {
        int cy = tile - 256;
        src = W + (size_t)cy * 128 * 256;
        dstTile = wT + (size_t)cy * TILE_BYTES;
    }
    const int t = threadIdx.x;

    // load 64 rows x 256 k, coalesced
    #pragma unroll
    for (int i = 0; i < 16; ++i) {
        int c = i * 256 + t;              // 0..4095
        int row = c >> 6, kq = c & 63;
        float4 v = *reinterpret_cast<const float4*>(
            src + ((size_t)(h * 64 + row)) * 256 + kq * 4);
        *reinterpret_cast<float4*>(&ls[row * 260 + kq * 4]) = v;
    }
    __syncthreads();

    // emit 4096 16B chunks, coalesced (slot fastest)
    #pragma unroll
    for (int j = 0; j < 16; ++j) {
        int q = j * 256 + t;              // 0..4095
        int slot = q & 63;
        int sp = (q >> 6) & 1;
        int rtl = (q >> 7) & 1;
        int kk = (q >> 8) & 1;
        int st = q >> 9;                  // 0..7
        int rowl = rtl * 32 + (slot & 31);
        int k = st * 32 + kk * 16 + (slot >> 5) * 8;
        const float* p = &ls[rowl * 260 + k];
        f16x8 o;
        if (sp == 0) {
            #pragma unroll
            for (int i = 0; i < 8; ++i) o[i] = (_Float16)p[i];
        } else {
            #pragma unroll
            for (int i = 0; i < 8; ++i) {
                _Float16 hv = (_Float16)p[i];
                o[i] = (_Float16)((p[i] - (float)hv) * 4096.0f);
            }
        }
        int rt = h * 2 + rtl;
        size_t off = ((((size_t)(st * 2 + kk) * 4 + rt) * 2 + sp) * 64 + slot) * 16;
        *reinterpret_cast<f16x8*>(dstTile + off) = o;
    }
}

// ---------------------------------------------------------------------------
// main GEMM: fp16-split MFMA (scores = relu(x @ W^T)) + per-column argmax.
// Staging: global_load_lds of contiguous 1KB chunks from the transformed
// layout (perfect coalescing), 2-phase double-buffered (STAGE(t+1) issued
// before COMPUTE(t); one barrier+drain per stage). BK=32 (2 kk per stage).
// ---------------------------------------------------------------------------
__global__ __launch_bounds__(256, 2) void gemm_argmax_t_kernel(
    const char* __restrict__ xT, const char* __restrict__ wT,
    u64* __restrict__ keys)
{
    __shared__ __align__(16) char lds[2][32768];   // [buf][A 16KB | B 16KB]

    const int tid = threadIdx.x;
    const int lane = tid & 63;
    const int w = tid >> 6;
    const int wy = w >> 1, wx = w & 1;
    const int pt = blockIdx.x;
    const int cy = blockIdx.y;
    const int b  = blockIdx.z;
    const int p0 = pt * TM;
    const int c0 = cy * TN;

    const char* aTile = xT + ((size_t)(b * 32 + pt)) * TILE_BYTES;
    const char* bTile = wT + (size_t)cy * TILE_BYTES;

    // this wave's staging source/dst: waves 0,1 stage A; waves 2,3 stage B.
    const char* mySrc = (w < 2 ? aTile : bTile) + (size_t)((w & 1) * 8) * 1024 + (size_t)lane * 16;
    const int myDstOff = (w >= 2 ? 16384 : 0) + (w & 1) * 8192;

    f32x16 zero;
    #pragma unroll
    for (int i = 0; i < 16; ++i) zero[i] = 0.f;
    f32x16 acc_hi[2][2], acc_lo[2][2];
    #pragma unroll
    for (int i = 0; i < 2; ++i)
        #pragma unroll
        for (int j = 0; j < 2; ++j) { acc_hi[i][j] = zero; acc_lo[i][j] = zero; }

    // prologue: stage st=0 into buf 0
    #pragma unroll
    for (int i = 0; i < 8; ++i)
        async_load16(mySrc + (size_t)i * 1024, &lds[0][myDstOff + i * 1024]);
    __syncthreads();   // drains vmcnt(0)

    for (int st = 0; st < 8; ++st) {
        const int buf = st & 1;
        if (st < 7) {
            const char* s = mySrc + (size_t)(st + 1) * 16384;
            #pragma unroll
            for (int i = 0; i < 8; ++i)
                async_load16(s + (size_t)i * 1024, &lds[buf ^ 1][myDstOff + i * 1024]);
        }
        const f16x8* A = (const f16x8*)&lds[buf][0];
        const f16x8* B = (const f16x8*)&lds[buf][16384];
        #pragma unroll
        for (int kk = 0; kk < 2; ++kk) {
            f16x8 xa[2][2], wb2[2][2];
            #pragma unroll
            for (int rt = 0; rt < 2; ++rt) {
                const int rg = wy * 2 + rt;
                xa[rt][0] = A[((kk * 4 + rg) * 2 + 0) * 64 + lane];
                xa[rt][1] = A[((kk * 4 + rg) * 2 + 1) * 64 + lane];
            }
            #pragma unroll
            for (int ct = 0; ct < 2; ++ct) {
                const int cg = wx * 2 + ct;
                wb2[ct][0] = B[((kk * 4 + cg) * 2 + 0) * 64 + lane];
                wb2[ct][1] = B[((kk * 4 + cg) * 2 + 1) * 64 + lane];
            }
            #pragma unroll
            for (int rt = 0; rt < 2; ++rt)
                #pragma unroll
                for (int ct = 0; ct < 2; ++ct) {
                    acc_hi[rt][ct] = __builtin_amdgcn_mfma_f32_32x32x16_f16(
                        xa[rt][0], wb2[ct][0], acc_hi[rt][ct], 0, 0, 0);
                    acc_lo[rt][ct] = __builtin_amdgcn_mfma_f32_32x32x16_f16(
                        xa[rt][0], wb2[ct][1], acc_lo[rt][ct], 0, 0, 0);
                    acc_lo[rt][ct] = __builtin_amdgcn_mfma_f32_32x32x16_f16(
                        xa[rt][1], wb2[ct][0], acc_lo[rt][ct], 0, 0, 0);
                }
        }
        __syncthreads();   // next-stage loads landed; buf free for overwrite
    }

    // ---- epilogue: per-column argmax over this block's 128 rows ----
    u64* smax = reinterpret_cast<u64*>(&lds[0][0]);
    if (tid < TN) smax[tid] = 0ull;
    __syncthreads();

    #pragma unroll
    for (int ct = 0; ct < 2; ++ct) {
        u64 bk = 0ull;
        #pragma unroll
        for (int rt = 0; rt < 2; ++rt) {
            f32x16 h = acc_hi[rt][ct];
            f32x16 l = acc_lo[rt][ct];
            #pragma unroll
            for (int reg = 0; reg < 16; ++reg) {
                float v = fmaxf(h[reg] + l[reg] * (1.0f / 4096.0f), 0.f);
                int prow = p0 + (wy * 2 + rt) * 32 +
                           (reg & 3) + 8 * (reg >> 2) + 4 * (lane >> 5);
                u64 key = ((u64)__float_as_uint(v) << 32) |
                          (unsigned int)(0xFFFFFFFFu - (unsigned int)prow);
                bk = bk > key ? bk : key;
            }
        }
        u64 other = __shfl_xor(bk, 32, 64);
        bk = bk > other ? bk : other;
        if (lane < 32) {
            int col = (wx * 2 + ct) * 32 + (lane & 31);
            atomicMax(&smax[col], bk);
        }
    }
    __syncthreads();
    if (tid < TN) {
        atomicMax(&keys[(size_t)b * CC + c0 + tid], smax[tid]);
    }
}

// ---------------------------------------------------------------------------
// fallback (ws too small): in-kernel conversion version (round-2, verified)
// ---------------------------------------------------------------------------
__global__ __launch_bounds__(256, 2) void gemm_argmax_conv_kernel(
    const float* __restrict__ x, const float* __restrict__ W,
    u64* __restrict__ keys)
{
    __shared__ f16x8 lA[4][4][2][64];
    __shared__ f16x8 lB[4][4][2][64];

    const int tid = threadIdx.x;
    const int lane = tid & 63;
    const int w = tid >> 6;
    const int wy = w >> 1, wx = w & 1;
    const int p0 = blockIdx.x * TM;
    const int c0 = blockIdx.y * TN;
    const int b  = blockIdx.z;

    const float* xb = x + (size_t)b * PP * DD;

    f32x16 zero;
    #pragma unroll
    for (int i = 0; i < 16; ++i) zero[i] = 0.f;
    f32x16 acc_hi[2][2], acc_lo[2][2];
    #pragma unroll
    for (int i = 0; i < 2; ++i)
        #pragma unroll
        for (int j = 0; j < 2; ++j) { acc_hi[i][j] = zero; acc_lo[i][j] = zero; }

    for (int st = 0; st < 4; ++st) {
        const int k0 = st * 64;
        float4 gA[8], gB[8];
        #pragma unroll
        for (int v = 0; v < 4; ++v) {
            int pi = tid + 256 * v;
            int r  = pi >> 3;
            int ck = (pi & 7) * 8;
            const float* pa = xb + (size_t)(p0 + r) * DD + k0 + ck;
            gA[2 * v]     = *reinterpret_cast<const float4*>(pa);
            gA[2 * v + 1] = *reinterpret_cast<const float4*>(pa + 4);
            const float* pb = W + (size_t)(c0 + r) * DD + k0 + ck;
            gB[2 * v]     = *reinterpret_cast<const float4*>(pb);
            gB[2 * v + 1] = *reinterpret_cast<const float4*>(pb + 4);
        }
        __syncthreads();
        #pragma unroll
        for (int v = 0; v < 4; ++v) {
            int pi = tid + 256 * v;
            int r  = pi >> 3;
            int ph = pi & 7;
            int kk = ph >> 1;
            int half = ph & 1;
            int slot = (r & 31) + 32 * half;
            int rtp = r >> 5;
            float va[8] = {gA[2*v].x, gA[2*v].y, gA[2*v].z, gA[2*v].w,
                           gA[2*v+1].x, gA[2*v+1].y, gA[2*v+1].z, gA[2*v+1].w};
            f16x8 h1, h2;
            #pragma unroll
            for (int i = 0; i < 8; ++i) {
                _Float16 h = (_Float16)va[i];
                h1[i] = h;
                h2[i] = (_Float16)((va[i] - (float)h) * 4096.0f);
            }
            lA[kk][rtp][0][slot] = h1;
            lA[kk][rtp][1][slot] = h2;
            float vb[8] = {gB[2*v].x, gB[2*v].y, gB[2*v].z, gB[2*v].w,
                           gB[2*v+1].x, gB[2*v+1].y, gB[2*v+1].z, gB[2*v+1].w};
            f16x8 g1, g2;
            #pragma unroll
            for (int i = 0; i < 8; ++i) {
                _Float16 h = (_Float16)vb[i];
                g1[i] = h;
                g2[i] = (_Float16)((vb[i] - (float)h) * 4096.0f);
            }
            lB[kk][rtp][0][slot] = g1;
            lB[kk][rtp][1][slot] = g2;
        }
        __syncthreads();
        #pragma unroll
        for (int kk = 0; kk < 4; ++kk) {
            f16x8 xa[2][2], wb2[2][2];
            #pragma unroll
            for (int rt = 0; rt < 2; ++rt) {
                xa[rt][0] = lA[kk][wy * 2 + rt][0][lane];
                xa[rt][1] = lA[kk][wy * 2 + rt][1][lane];
            }
            #pragma unroll
            for (int ct = 0; ct < 2; ++ct) {
                wb2[ct][0] = lB[kk][wx * 2 + ct][0][lane];
                wb2[ct][1] = lB[kk][wx * 2 + ct][1][lane];
            }
            #pragma unroll
            for (int rt = 0; rt < 2; ++rt)
                #pragma unroll
                for (int ct = 0; ct < 2; ++ct) {
                    acc_hi[rt][ct] = __builtin_amdgcn_mfma_f32_32x32x16_f16(
                        xa[rt][0], wb2[ct][0], acc_hi[rt][ct], 0, 0, 0);
                    acc_lo[rt][ct] = __builtin_amdgcn_mfma_f32_32x32x16_f16(
                        xa[rt][0], wb2[ct][1], acc_lo[rt][ct], 0, 0, 0);
                    acc_lo[rt][ct] = __builtin_amdgcn_mfma_f32_32x32x16_f16(
                        xa[rt][1], wb2[ct][0], acc_lo[rt][ct], 0, 0, 0);
                }
        }
    }

    u64* smax = reinterpret_cast<u64*>(&lA[0][0][0][0]);
    __syncthreads();
    if (tid < TN) smax[tid] = 0ull;
    __syncthreads();

    #pragma unroll
    for (int ct = 0; ct < 2; ++ct) {
        u64 bk = 0ull;
        #pragma unroll
        for (int rt = 0; rt < 2; ++rt) {
            f32x16 h = acc_hi[rt][ct];
            f32x16 l = acc_lo[rt][ct];
            #pragma unroll
            for (int reg = 0; reg < 16; ++reg) {
                float v = fmaxf(h[reg] + l[reg] * (1.0f / 4096.0f), 0.f);
                int prow = p0 + (wy * 2 + rt) * 32 +
                           (reg & 3) + 8 * (reg >> 2) + 4 * (lane >> 5);
                u64 key = ((u64)__float_as_uint(v) << 32) |
                          (unsigned int)(0xFFFFFFFFu - (unsigned int)prow);
                bk = bk > key ? bk : key;
            }
        }
        u64 other = __shfl_xor(bk, 32, 64);
        bk = bk > other ? bk : other;
        if (lane < 32) {
            int col = (wx * 2 + ct) * 32 + (lane & 31);
            atomicMax(&smax[col], bk);
        }
    }
    __syncthreads();
    if (tid < TN) {
        atomicMax(&keys[(size_t)b * CC + c0 + tid], smax[tid]);
    }
}

// ---------------------------------------------------------------------------
// scatter: out[b, argmax_p(b,c), :] += W[c, :]
// ---------------------------------------------------------------------------
__global__ __launch_bounds__(64) void scatter_kernel(
    const u64* __restrict__ keys,
    const float* __restrict__ W,
    float* __restrict__ out)
{
    const int cell = blockIdx.x;
    const int c = cell & (CC - 1);
    const int b = cell >> 10;
    u64 key = keys[cell];
    unsigned int p = (0xFFFFFFFFu - (unsigned int)(key & 0xFFFFFFFFull)) & (PP - 1);

    const float* wrow = W + (size_t)c * DD;
    float* orow = out + ((size_t)b * PP + p) * DD;
    const int t = threadIdx.x;
    #pragma unroll
    for (int u = 0; u < 4; u++) {
        int idx = u * 64 + t;
        atomicAdd(&orow[idx], wrow[idx]);
    }
}

extern "C" void kernel_launch(void* const* d_in, const int* in_sizes, int n_in,
                              void* d_out, int out_size, void* d_ws, size_t ws_size,
                              hipStream_t stream) {
    const float* x = (const float*)d_in[0];   // [B, P, D] fp32
    const float* W = (const float*)d_in[1];   // [C, D]    fp32
    float* out = (float*)d_out;

    char* wsb = (char*)d_ws;
    u64* keys = (u64*)wsb;                          // 64 KB
    char* xT = wsb + 65536;
    char* wT = xT + XT_BYTES;
    const size_t need = 65536 + XT_BYTES + WT_BYTES;

    hipMemsetAsync(d_out, 0, (size_t)out_size * sizeof(float), stream);

    {
        int n = BB * CC;
        init_ws_kernel<<<(n + 255) / 256, 256, 0, stream>>>(keys, n);
    }

    if (ws_size >= need) {
        transform_kernel<<<528, 256, 0, stream>>>(x, W, xT, wT);
        dim3 grid(PP / TM, CC / TN, BB);
        gemm_argmax_t_kernel<<<grid, 256, 0, stream>>>(xT, wT, keys);
    } else {
        dim3 grid(PP / TM, CC / TN, BB);
        gemm_argmax_conv_kernel<<<grid, 256, 0, stream>>>(x, W, keys);
    }

    {
        dim3 grid(BB * CC);
        scatter_kernel<<<grid, 64, 0, stream>>>(keys, W, out);
    }
}

// Round 5
// 86.491 us; speedup vs baseline: 2.7085x; 1.0174x over previous
//
#include <hip/hip_runtime.h>
#include <cstdint>

#define BB 8
#define PP 4096
#define DD 256
#define CC 1024

#define TM 128
#define TN 128

#define XT_BYTES (33554432ull)   // 8*32 tiles * 128KB
#define WT_BYTES (1048576ull)    // 8 chunks * 128KB
#define TILE_BYTES 131072ull     // one (b,pt) or cy chunk: 128 rows x 256 k x 2 planes x 2B

typedef _Float16 f16x8 __attribute__((ext_vector_type(8)));
typedef float f32x16 __attribute__((ext_vector_type(16)));
typedef unsigned long long u64;

__device__ __forceinline__ void async_load16(const void* src, void* lds_dst) {
    __builtin_amdgcn_global_load_lds(
        (const __attribute__((address_space(1))) uint32_t*)src,
        (__attribute__((address_space(3))) uint32_t*)lds_dst,
        16, 0, 0);
}

// ---------------------------------------------------------------------------
// init argmax cells (fallback path only): score 0.0 @ p=0
// ---------------------------------------------------------------------------
__global__ __launch_bounds__(256) void init_ws_kernel(u64* keys, int n) {
    int i = blockIdx.x * 256 + threadIdx.x;
    if (i < n) keys[i] = 0x00000000FFFFFFFFull;
}

// ---------------------------------------------------------------------------
// transform: fp32 [rows][256] -> fragment-ordered fp16 hi/lo planes.
// Output chunk (st,kk,rt,sp,slot) of 16B; slot = (row&31) + 32*ksub.
// Blocks 0..31 additionally init the 8192 argmax key cells (fused init).
// grid = 528: ids 0..511 -> x tile (id>>1), h=id&1; 512..527 -> W chunk.
// ---------------------------------------------------------------------------
__global__ __launch_bounds__(256) void transform_kernel(
    const float* __restrict__ x, const float* __restrict__ W,
    char* __restrict__ xT, char* __restrict__ wT, u64* __restrict__ keys)
{
    __shared__ float ls[64 * 260];   // 64 rows, stride 260 (pad: f4-aligned)

    const int id = blockIdx.x;
    const int t = threadIdx.x;
    if (id < 32) keys[id * 256 + t] = 0x00000000FFFFFFFFull;

    const int tile = id >> 1;
    const int h = id & 1;
    const float* src;
    char* dstTile;
    if (tile < 256) {
        src = x + (size_t)tile * 128 * 256;          // tile = b*32+pt
        dstTile = xT + (size_t)tile * TILE_BYTES;
    } else {
        int cy = tile - 256;
        src = W + (size_t)cy * 128 * 256;
        dstTile = wT + (size_t)cy * TILE_BYTES;
    }

    // load 64 rows x 256 k, coalesced
    #pragma unroll
    for (int i = 0; i < 16; ++i) {
        int c = i * 256 + t;              // 0..4095
        int row = c >> 6, kq = c & 63;
        float4 v = *reinterpret_cast<const float4*>(
            src + ((size_t)(h * 64 + row)) * 256 + kq * 4);
        *reinterpret_cast<float4*>(&ls[row * 260 + kq * 4]) = v;
    }
    __syncthreads();

    // emit 4096 16B chunks, coalesced (slot fastest)
    #pragma unroll
    for (int j = 0; j < 16; ++j) {
        int q = j * 256 + t;              // 0..4095
        int slot = q & 63;
        int sp = (q >> 6) & 1;
        int rtl = (q >> 7) & 1;
        int kk = (q >> 8) & 1;
        int st = q >> 9;                  // 0..7
        int rowl = rtl * 32 + (slot & 31);
        int k = st * 32 + kk * 16 + (slot >> 5) * 8;
        const float* p = &ls[rowl * 260 + k];
        f16x8 o;
        if (sp == 0) {
            #pragma unroll
            for (int i = 0; i < 8; ++i) o[i] = (_Float16)p[i];
        } else {
            #pragma unroll
            for (int i = 0; i < 8; ++i) {
                _Float16 hv = (_Float16)p[i];
                o[i] = (_Float16)((p[i] - (float)hv) * 4096.0f);
            }
        }
        int rt = h * 2 + rtl;
        size_t off = ((((size_t)(st * 2 + kk) * 4 + rt) * 2 + sp) * 64 + slot) * 16;
        *reinterpret_cast<f16x8*>(dstTile + off) = o;
    }
}

// ---------------------------------------------------------------------------
// main GEMM: fp16-split MFMA (scores = relu(x @ W^T)) + per-column argmax.
// Counted-vmcnt pipeline (T4): prologue issues stages 0 and 1; each stage
// waits vmcnt(8) (own 8 loads done, next stage's 8 in flight), raw s_barrier,
// compute, lgkmcnt(0)+s_barrier, then issues stage st+2 into the freed
// buffer. No vmcnt(0) drain in the main loop. T5 setprio around MFMAs.
// ---------------------------------------------------------------------------
__global__ __launch_bounds__(256, 2) void gemm_argmax_t_kernel(
    const char* __restrict__ xT, const char* __restrict__ wT,
    u64* __restrict__ keys)
{
    __shared__ __align__(16) char lds[2][32768];   // [buf][A 16KB | B 16KB]

    const int tid = threadIdx.x;
    const int lane = tid & 63;
    const int w = tid >> 6;
    const int wy = w >> 1, wx = w & 1;
    const int pt = blockIdx.x;
    const int cy = blockIdx.y;
    const int b  = blockIdx.z;
    const int p0 = pt * TM;
    const int c0 = cy * TN;

    const char* aTile = xT + ((size_t)(b * 32 + pt)) * TILE_BYTES;
    const char* bTile = wT + (size_t)cy * TILE_BYTES;

    // this wave's staging source/dst: waves 0,1 stage A; waves 2,3 stage B.
    const char* mySrc = (w < 2 ? aTile : bTile) + (size_t)((w & 1) * 8) * 1024 + (size_t)lane * 16;
    const int myDstOff = (w >= 2 ? 16384 : 0) + (w & 1) * 8192;

    f32x16 zero;
    #pragma unroll
    for (int i = 0; i < 16; ++i) zero[i] = 0.f;
    f32x16 acc_hi[2][2], acc_lo[2][2];
    #pragma unroll
    for (int i = 0; i < 2; ++i)
        #pragma unroll
        for (int j = 0; j < 2; ++j) { acc_hi[i][j] = zero; acc_lo[i][j] = zero; }

    // prologue: stage st=0 into buf0 and st=1 into buf1 (16 loads in flight)
    #pragma unroll
    for (int i = 0; i < 8; ++i)
        async_load16(mySrc + (size_t)i * 1024, &lds[0][myDstOff + i * 1024]);
    #pragma unroll
    for (int i = 0; i < 8; ++i)
        async_load16(mySrc + 16384 + (size_t)i * 1024, &lds[1][myDstOff + i * 1024]);

    #pragma unroll
    for (int st = 0; st < 8; ++st) {
        const int buf = st & 1;
        // wait for this stage's 8 loads; next stage's 8 remain in flight
        if (st < 7) asm volatile("s_waitcnt vmcnt(8)" ::: "memory");
        else        asm volatile("s_waitcnt vmcnt(0)" ::: "memory");
        __builtin_amdgcn_s_barrier();

        const f16x8* A = (const f16x8*)&lds[buf][0];
        const f16x8* B = (const f16x8*)&lds[buf][16384];
        __builtin_amdgcn_s_setprio(1);
        #pragma unroll
        for (int kk = 0; kk < 2; ++kk) {
            f16x8 xa[2][2], wb2[2][2];
            #pragma unroll
            for (int rt = 0; rt < 2; ++rt) {
                const int rg = wy * 2 + rt;
                xa[rt][0] = A[((kk * 4 + rg) * 2 + 0) * 64 + lane];
                xa[rt][1] = A[((kk * 4 + rg) * 2 + 1) * 64 + lane];
            }
            #pragma unroll
            for (int ct = 0; ct < 2; ++ct) {
                const int cg = wx * 2 + ct;
                wb2[ct][0] = B[((kk * 4 + cg) * 2 + 0) * 64 + lane];
                wb2[ct][1] = B[((kk * 4 + cg) * 2 + 1) * 64 + lane];
            }
            #pragma unroll
            for (int rt = 0; rt < 2; ++rt)
                #pragma unroll
                for (int ct = 0; ct < 2; ++ct) {
                    acc_hi[rt][ct] = __builtin_amdgcn_mfma_f32_32x32x16_f16(
                        xa[rt][0], wb2[ct][0], acc_hi[rt][ct], 0, 0, 0);
                    acc_lo[rt][ct] = __builtin_amdgcn_mfma_f32_32x32x16_f16(
                        xa[rt][0], wb2[ct][1], acc_lo[rt][ct], 0, 0, 0);
                    acc_lo[rt][ct] = __builtin_amdgcn_mfma_f32_32x32x16_f16(
                        xa[rt][1], wb2[ct][0], acc_lo[rt][ct], 0, 0, 0);
                }
        }
        __builtin_amdgcn_s_setprio(0);

        // all LDS reads of buf complete, then barrier; only now may the
        // next prefetch overwrite buf
        asm volatile("s_waitcnt lgkmcnt(0)" ::: "memory");
        __builtin_amdgcn_s_barrier();
        if (st + 2 < 8) {
            const char* s = mySrc + (size_t)(st + 2) * 16384;
            #pragma unroll
            for (int i = 0; i < 8; ++i)
                async_load16(s + (size_t)i * 1024, &lds[buf][myDstOff + i * 1024]);
        }
    }

    // ---- epilogue: per-column argmax over this block's 128 rows ----
    u64* smax = reinterpret_cast<u64*>(&lds[0][0]);
    if (tid < TN) smax[tid] = 0ull;
    __syncthreads();

    #pragma unroll
    for (int ct = 0; ct < 2; ++ct) {
        u64 bk = 0ull;
        #pragma unroll
        for (int rt = 0; rt < 2; ++rt) {
            f32x16 h = acc_hi[rt][ct];
            f32x16 l = acc_lo[rt][ct];
            #pragma unroll
            for (int reg = 0; reg < 16; ++reg) {
                float v = fmaxf(h[reg] + l[reg] * (1.0f / 4096.0f), 0.f);
                int prow = p0 + (wy * 2 + rt) * 32 +
                           (reg & 3) + 8 * (reg >> 2) + 4 * (lane >> 5);
                u64 key = ((u64)__float_as_uint(v) << 32) |
                          (unsigned int)(0xFFFFFFFFu - (unsigned int)prow);
                bk = bk > key ? bk : key;
            }
        }
        u64 other = __shfl_xor(bk, 32, 64);
        bk = bk > other ? bk : other;
        if (lane < 32) {
            int col = (wx * 2 + ct) * 32 + (lane & 31);
            atomicMax(&smax[col], bk);
        }
    }
    __syncthreads();
    if (tid < TN) {
        atomicMax(&keys[(size_t)b * CC + c0 + tid], smax[tid]);
    }
}

// ---------------------------------------------------------------------------
// fallback (ws too small): in-kernel conversion version (round-2, verified)
// ---------------------------------------------------------------------------
__global__ __launch_bounds__(256, 2) void gemm_argmax_conv_kernel(
    const float* __restrict__ x, const float* __restrict__ W,
    u64* __restrict__ keys)
{
    __shared__ f16x8 lA[4][4][2][64];
    __shared__ f16x8 lB[4][4][2][64];

    const int tid = threadIdx.x;
    const int lane = tid & 63;
    const int w = tid >> 6;
    const int wy = w >> 1, wx = w & 1;
    const int p0 = blockIdx.x * TM;
    const int c0 = blockIdx.y * TN;
    const int b  = blockIdx.z;

    const float* xb = x + (size_t)b * PP * DD;

    f32x16 zero;
    #pragma unroll
    for (int i = 0; i < 16; ++i) zero[i] = 0.f;
    f32x16 acc_hi[2][2], acc_lo[2][2];
    #pragma unroll
    for (int i = 0; i < 2; ++i)
        #pragma unroll
        for (int j = 0; j < 2; ++j) { acc_hi[i][j] = zero; acc_lo[i][j] = zero; }

    for (int st = 0; st < 4; ++st) {
        const int k0 = st * 64;
        float4 gA[8], gB[8];
        #pragma unroll
        for (int v = 0; v < 4; ++v) {
            int pi = tid + 256 * v;
            int r  = pi >> 3;
            int ck = (pi & 7) * 8;
            const float* pa = xb + (size_t)(p0 + r) * DD + k0 + ck;
            gA[2 * v]     = *reinterpret_cast<const float4*>(pa);
            gA[2 * v + 1] = *reinterpret_cast<const float4*>(pa + 4);
            const float* pb = W + (size_t)(c0 + r) * DD + k0 + ck;
            gB[2 * v]     = *reinterpret_cast<const float4*>(pb);
            gB[2 * v + 1] = *reinterpret_cast<const float4*>(pb + 4);
        }
        __syncthreads();
        #pragma unroll
        for (int v = 0; v < 4; ++v) {
            int pi = tid + 256 * v;
            int r  = pi >> 3;
            int ph = pi & 7;
            int kk = ph >> 1;
            int half = ph & 1;
            int slot = (r & 31) + 32 * half;
            int rtp = r >> 5;
            float va[8] = {gA[2*v].x, gA[2*v].y, gA[2*v].z, gA[2*v].w,
                           gA[2*v+1].x, gA[2*v+1].y, gA[2*v+1].z, gA[2*v+1].w};
            f16x8 h1, h2;
            #pragma unroll
            for (int i = 0; i < 8; ++i) {
                _Float16 h = (_Float16)va[i];
                h1[i] = h;
                h2[i] = (_Float16)((va[i] - (float)h) * 4096.0f);
            }
            lA[kk][rtp][0][slot] = h1;
            lA[kk][rtp][1][slot] = h2;
            float vb[8] = {gB[2*v].x, gB[2*v].y, gB[2*v].z, gB[2*v].w,
                           gB[2*v+1].x, gB[2*v+1].y, gB[2*v+1].z, gB[2*v+1].w};
            f16x8 g1, g2;
            #pragma unroll
            for (int i = 0; i < 8; ++i) {
                _Float16 h = (_Float16)vb[i];
                g1[i] = h;
                g2[i] = (_Float16)((vb[i] - (float)h) * 4096.0f);
            }
            lB[kk][rtp][0][slot] = g1;
            lB[kk][rtp][1][slot] = g2;
        }
        __syncthreads();
        #pragma unroll
        for (int kk = 0; kk < 4; ++kk) {
            f16x8 xa[2][2], wb2[2][2];
            #pragma unroll
            for (int rt = 0; rt < 2; ++rt) {
                xa[rt][0] = lA[kk][wy * 2 + rt][0][lane];
                xa[rt][1] = lA[kk][wy * 2 + rt][1][lane];
            }
            #pragma unroll
            for (int ct = 0; ct < 2; ++ct) {
                wb2[ct][0] = lB[kk][wx * 2 + ct][0][lane];
                wb2[ct][1] = lB[kk][wx * 2 + ct][1][lane];
            }
            #pragma unroll
            for (int rt = 0; rt < 2; ++rt)
                #pragma unroll
                for (int ct = 0; ct < 2; ++ct) {
                    acc_hi[rt][ct] = __builtin_amdgcn_mfma_f32_32x32x16_f16(
                        xa[rt][0], wb2[ct][0], acc_hi[rt][ct], 0, 0, 0);
                    acc_lo[rt][ct] = __builtin_amdgcn_mfma_f32_32x32x16_f16(
                        xa[rt][0], wb2[ct][1], acc_lo[rt][ct], 0, 0, 0);
                    acc_lo[rt][ct] = __builtin_amdgcn_mfma_f32_32x32x16_f16(
                        xa[rt][1], wb2[ct][0], acc_lo[rt][ct], 0, 0, 0);
                }
        }
    }

    u64* smax = reinterpret_cast<u64*>(&lA[0][0][0][0]);
    __syncthreads();
    if (tid < TN) smax[tid] = 0ull;
    __syncthreads();

    #pragma unroll
    for (int ct = 0; ct < 2; ++ct) {
        u64 bk = 0ull;
        #pragma unroll
        for (int rt = 0; rt < 2; ++rt) {
            f32x16 h = acc_hi[rt][ct];
            f32x16 l = acc_lo[rt][ct];
            #pragma unroll
            for (int reg = 0; reg < 16; ++reg) {
                float v = fmaxf(h[reg] + l[reg] * (1.0f / 4096.0f), 0.f);
                int prow = p0 + (wy * 2 + rt) * 32 +
                           (reg & 3) + 8 * (reg >> 2) + 4 * (lane >> 5);
                u64 key = ((u64)__float_as_uint(v) << 32) |
                          (unsigned int)(0xFFFFFFFFu - (unsigned int)prow);
                bk = bk > key ? bk : key;
            }
        }
        u64 other = __shfl_xor(bk, 32, 64);
        bk = bk > other ? bk : other;
        if (lane < 32) {
            int col = (wx * 2 + ct) * 32 + (lane & 31);
            atomicMax(&smax[col], bk);
        }
    }
    __syncthreads();
    if (tid < TN) {
        atomicMax(&keys[(size_t)b * CC + c0 + tid], smax[tid]);
    }
}

// ---------------------------------------------------------------------------
// scatter: out[b, argmax_p(b,c), :] += W[c, :]
// ---------------------------------------------------------------------------
__global__ __launch_bounds__(64) void scatter_kernel(
    const u64* __restrict__ keys,
    const float* __restrict__ W,
    float* __restrict__ out)
{
    const int cell = blockIdx.x;
    const int c = cell & (CC - 1);
    const int b = cell >> 10;
    u64 key = keys[cell];
    unsigned int p = (0xFFFFFFFFu - (unsigned int)(key & 0xFFFFFFFFull)) & (PP - 1);

    const float* wrow = W + (size_t)c * DD;
    float* orow = out + ((size_t)b * PP + p) * DD;
    const int t = threadIdx.x;
    #pragma unroll
    for (int u = 0; u < 4; u++) {
        int idx = u * 64 + t;
        atomicAdd(&orow[idx], wrow[idx]);
    }
}

extern "C" void kernel_launch(void* const* d_in, const int* in_sizes, int n_in,
                              void* d_out, int out_size, void* d_ws, size_t ws_size,
                              hipStream_t stream) {
    const float* x = (const float*)d_in[0];   // [B, P, D] fp32
    const float* W = (const float*)d_in[1];   // [C, D]    fp32
    float* out = (float*)d_out;

    char* wsb = (char*)d_ws;
    u64* keys = (u64*)wsb;                          // 64 KB
    char* xT = wsb + 65536;
    char* wT = xT + XT_BYTES;
    const size_t need = 65536 + XT_BYTES + WT_BYTES;

    hipMemsetAsync(d_out, 0, (size_t)out_size * sizeof(float), stream);

    if (ws_size >= need) {
        transform_kernel<<<528, 256, 0, stream>>>(x, W, xT, wT, keys);
        dim3 grid(PP / TM, CC / TN, BB);
        gemm_argmax_t_kernel<<<grid, 256, 0, stream>>>(xT, wT, keys);
    } else {
        int n = BB * CC;
        init_ws_kernel<<<(n + 255) / 256, 256, 0, stream>>>(keys, n);
        dim3 grid(PP / TM, CC / TN, BB);
        gemm_argmax_conv_kernel<<<grid, 256, 0, stream>>>(x, W, keys);
    }

    {
        dim3 grid(BB * CC);
        scatter_kernel<<<grid, 64, 0, stream>>>(keys, W, out);
    }
}